// Round 16
// baseline (599.465 us; speedup 1.0000x reference)
//
#include <hip/hip_runtime.h>

#define NUM_EMB 512
#define DIM 64
#define HW 4096          // 64*64 spatial
#define NPOS 131072      // 32 * 4096
#define XELEMS 8388608   // 32*64*4096 — one output copy
#define KHALF 256        // codebook rows per k-half
#define POSB 128         // positions per block (256 thr = 128 pos x 2 halves)

// ---------------------------------------------------------------------------
// Kernel 1: per-codebook-row squared norms -> d_ws (512 floats)
// ---------------------------------------------------------------------------
__global__ void vq_esq_kernel(const float* __restrict__ e, float* __restrict__ esq) {
    int k = blockIdx.x * blockDim.x + threadIdx.x;
    if (k < NUM_EMB) {
        const float4* er = reinterpret_cast<const float4*>(e + k * DIM);
        float s = 0.f;
#pragma unroll
        for (int i = 0; i < DIM / 4; ++i) {
            float4 v = er[i];
            s += v.x * v.x + v.y * v.y + v.z * v.z + v.w * v.w;
        }
        esq[k] = s;
    }
}

// ---------------------------------------------------------------------------
// Kernel 2: main VQ.
//
// R7 evidence: asm-pin worked (VGPR 56->88) yet dur/VALUBusy unchanged
// (230us/30%). 30% != 2x34% -> the two resident waves did NOT antiphase-
// overlap: both serialize on the scalar-cache s_load stream (single-buffered
// 64-SGPR row; K$ shared per CU). Fix: take e-rows through the VECTOR path
// (global_load_dwordx4, same addr across lanes -> L1 broadcast), explicitly
// double-buffered in VGPRs. Prefetch distance = 1 row = 256cy of FMA > load
// latency -> each thread self-pipelines; no dependence on wave overlap or K$.
// The address is laundered through asm "+v" so divergence analysis keeps the
// load vector (inline-asm output = divergent).
//
// Layout: 256 thr/block = 128 positions x 2 k-halves; 1024 blocks.
// LDS combine preserves exact argmin-first-index semantics: strict '<'
// within a half; lower half wins cross-half ties. Distance arithmetic is
// bit-identical to the verified absmax==0.0 kernel.
// ---------------------------------------------------------------------------
__global__ __launch_bounds__(256)
__attribute__((amdgpu_waves_per_eu(2, 2)))
void vq_main_kernel(const float* __restrict__ x,
                    const float* __restrict__ e,
                    const float* __restrict__ esq,
                    float* __restrict__ out) {
    __shared__ float s_best[2][POSB];
    __shared__ int s_bk[2][POSB];

    const int t = threadIdx.x;
    const int half = t >> 7;  // 0: k in [0,256), 1: k in [256,512)
    const int tl = t & 127;   // position-local index

    const int pbase = blockIdx.x * POSB;  // 128-aligned -> single batch/block
    const int b = pbase >> 12;
    const int hwb = pbase & 4095;

    // Both halves load the SAME position tl (each half scans different rows).
    const float* xb = x + (size_t)b * (DIM * HW) + (hwb + tl);

    float xr[DIM];
#pragma unroll
    for (int d = 0; d < DIM; ++d) xr[d] = xb[(size_t)d * HW];
    // Pin x in VGPRs (asm = defining use -> no remat/sink; verified R7).
#pragma unroll
    for (int d = 0; d < DIM; d += 8) {
        asm volatile("" : "+v"(xr[d + 0]), "+v"(xr[d + 1]), "+v"(xr[d + 2]),
                          "+v"(xr[d + 3]), "+v"(xr[d + 4]), "+v"(xr[d + 5]),
                          "+v"(xr[d + 6]), "+v"(xr[d + 7]));
    }

    float xsq = 0.f;
#pragma unroll
    for (int d = 0; d < DIM; ++d) xsq = fmaf(xr[d], xr[d], xsq);

    float best = 3.4e38f;
    int bk = 0;
    const int kbeg = half * KHALF;
    const int klast = kbeg + KHALF - 1;

    // Vector-path row load: launder byte offset into a VGPR so the loads stay
    // on the TA/L1 path (uniform addr -> broadcast, one 16B line per load).
    auto loadrow = [&](float4* buf, int krow) {
        int off = krow * (DIM * 4);  // byte offset, max 512*256 = 131072
        asm volatile("" : "+v"(off));
        const float4* ek4 =
            reinterpret_cast<const float4*>(reinterpret_cast<const char*>(e) + off);
#pragma unroll
        for (int j = 0; j < 16; ++j) buf[j] = ek4[j];
    };
    auto fmarow = [&](const float4* buf, int krow) {
        float a0 = 0.f, a1 = 0.f, a2 = 0.f, a3 = 0.f;
#pragma unroll
        for (int j = 0; j < 16; ++j) {
            a0 = fmaf(xr[4 * j + 0], buf[j].x, a0);
            a1 = fmaf(xr[4 * j + 1], buf[j].y, a1);
            a2 = fmaf(xr[4 * j + 2], buf[j].z, a2);
            a3 = fmaf(xr[4 * j + 3], buf[j].w, a3);
        }
        float dot = (a0 + a1) + (a2 + a3);
        // identical rounding sequence to the verified kernel
        float dist = fmaf(-2.f, dot, xsq) + esq[krow];
        if (dist < best) { best = dist; bk = krow; }  // strict '<': first index
    };

    float4 bufA[16], bufB[16];
    loadrow(bufA, kbeg);
    for (int kk = 0; kk < KHALF; kk += 2) {
        int k0 = kbeg + kk;
        loadrow(bufB, k0 + 1);                      // prefetch next row
        fmarow(bufA, k0);
        int kn = (k0 + 2 > klast) ? klast : k0 + 2; // clamp: last prefetch unused
        loadrow(bufA, kn);
        fmarow(bufB, k0 + 1);
    }

    s_best[half][tl] = best;
    s_bk[half][tl] = bk;
    __syncthreads();

    // Both halves compute the winner for position tl; each writes ONE copy.
    float bl = s_best[0][tl];
    int kl = s_bk[0][tl];
    float bu = s_best[1][tl];
    int ku = s_bk[1][tl];
    int kw = (bu < bl) ? ku : kl;  // ties -> lower k (argmin first index)

    const float4* eb = reinterpret_cast<const float4*>(e + kw * DIM);
    float* o = out + (size_t)half * XELEMS + (size_t)b * (DIM * HW) + (hwb + tl);
#pragma unroll
    for (int i = 0; i < DIM / 4; ++i) {
        float4 v = eb[i];
        o[(size_t)(4 * i + 0) * HW] = v.x;
        o[(size_t)(4 * i + 1) * HW] = v.y;
        o[(size_t)(4 * i + 2) * HW] = v.z;
        o[(size_t)(4 * i + 3) * HW] = v.w;
    }
}

extern "C" void kernel_launch(void* const* d_in, const int* in_sizes, int n_in,
                              void* d_out, int out_size, void* d_ws, size_t ws_size,
                              hipStream_t stream) {
    const float* x = (const float*)d_in[0];
    const float* e = (const float*)d_in[1];
    float* out = (float*)d_out;
    float* esq = (float*)d_ws;  // 512 floats of scratch

    vq_esq_kernel<<<1, NUM_EMB, 0, stream>>>(e, esq);
    vq_main_kernel<<<NPOS / POSB, 256, 0, stream>>>(x, e, esq, out);
}

// Round 17
// 560.056 us; speedup vs baseline: 1.0704x; 1.0704x over previous
//
#include <hip/hip_runtime.h>

#define NUM_EMB 512
#define DIM 64
#define HW 4096          // 64*64 spatial
#define NPOS 131072      // 32 * 4096
#define XELEMS 8388608   // 32*64*4096 — one output copy
#define KHALF 256        // codebook rows per k-half
#define POSB 128         // positions per block (256 thr = 128 pos x 2 halves)

// ---------------------------------------------------------------------------
// Kernel 1: per-codebook-row squared norms -> d_ws (512 floats)
// ---------------------------------------------------------------------------
__global__ void vq_esq_kernel(const float* __restrict__ e, float* __restrict__ esq) {
    int k = blockIdx.x * blockDim.x + threadIdx.x;
    if (k < NUM_EMB) {
        const float4* er = reinterpret_cast<const float4*>(e + k * DIM);
        float s = 0.f;
#pragma unroll
        for (int i = 0; i < DIM / 4; ++i) {
            float4 v = er[i];
            s += v.x * v.x + v.y * v.y + v.z * v.z + v.w * v.w;
        }
        esq[k] = s;
    }
}

// ---------------------------------------------------------------------------
// Kernel 2: main VQ.
//
// R16 post-mortem: the float4 bufA[16]/bufB[16] accessed through lambda
// float4* params were NOT promoted (VGPR=112 -> scratch round-trip per row,
// 557us). Fix: NAMED float4 registers via macros — every access is a static
// identifier, forcing register allocation (rule #20).
//
// Theory (unchanged from R13): R7 showed the s_load path serializes the two
// resident waves (VALUBusy 30% != antiphase overlap). e-rows now go through
// the VECTOR path (uniform addr -> one 16B L1 line per load, laundered into
// a VGPR so uniformity analysis can't re-scalarize), double-buffered with
// prefetch distance = 1 row = 256 FMA-cycles > ~200cy L1/L2 latency ->
// each thread self-pipelines, independent of wave overlap and K$.
//
// 256 thr/block = 128 positions x 2 k-halves; LDS combine keeps exact
// argmin first-index ties (strict '<' in-half; lower half wins cross-half).
// Distance rounding identical to the verified absmax==0.0 kernel.
// ---------------------------------------------------------------------------
#define DECL_BUF(p) float4 p##0, p##1, p##2, p##3, p##4, p##5, p##6, p##7, \
                           p##8, p##9, p##10, p##11, p##12, p##13, p##14, p##15;

#define LOADROW(p, krow)                                                        \
    {                                                                           \
        int off_ = (krow) * (DIM * 4);                                          \
        asm volatile("" : "+v"(off_));                                          \
        const float4* ek4_ = reinterpret_cast<const float4*>(                   \
            reinterpret_cast<const char*>(e) + off_);                           \
        p##0 = ek4_[0];   p##1 = ek4_[1];   p##2 = ek4_[2];   p##3 = ek4_[3];   \
        p##4 = ek4_[4];   p##5 = ek4_[5];   p##6 = ek4_[6];   p##7 = ek4_[7];   \
        p##8 = ek4_[8];   p##9 = ek4_[9];   p##10 = ek4_[10]; p##11 = ek4_[11]; \
        p##12 = ek4_[12]; p##13 = ek4_[13]; p##14 = ek4_[14]; p##15 = ek4_[15]; \
    }

#define FMA4(p, j, a0, a1, a2, a3)                 \
    a0 = fmaf(xr[4 * j + 0], p##j.x, a0);          \
    a1 = fmaf(xr[4 * j + 1], p##j.y, a1);          \
    a2 = fmaf(xr[4 * j + 2], p##j.z, a2);          \
    a3 = fmaf(xr[4 * j + 3], p##j.w, a3);

#define FMAROW(p, krow)                                                         \
    {                                                                           \
        float a0 = 0.f, a1 = 0.f, a2 = 0.f, a3 = 0.f;                           \
        FMA4(p, 0, a0, a1, a2, a3)  FMA4(p, 1, a0, a1, a2, a3)                  \
        FMA4(p, 2, a0, a1, a2, a3)  FMA4(p, 3, a0, a1, a2, a3)                  \
        FMA4(p, 4, a0, a1, a2, a3)  FMA4(p, 5, a0, a1, a2, a3)                  \
        FMA4(p, 6, a0, a1, a2, a3)  FMA4(p, 7, a0, a1, a2, a3)                  \
        FMA4(p, 8, a0, a1, a2, a3)  FMA4(p, 9, a0, a1, a2, a3)                  \
        FMA4(p, 10, a0, a1, a2, a3) FMA4(p, 11, a0, a1, a2, a3)                 \
        FMA4(p, 12, a0, a1, a2, a3) FMA4(p, 13, a0, a1, a2, a3)                 \
        FMA4(p, 14, a0, a1, a2, a3) FMA4(p, 15, a0, a1, a2, a3)                 \
        float dot_ = (a0 + a1) + (a2 + a3);                                     \
        float dist_ = fmaf(-2.f, dot_, xsq) + esq[(krow)];                      \
        if (dist_ < best) { best = dist_; bk = (krow); }                        \
    }

__global__ __launch_bounds__(256)
__attribute__((amdgpu_waves_per_eu(2, 2)))
void vq_main_kernel(const float* __restrict__ x,
                    const float* __restrict__ e,
                    const float* __restrict__ esq,
                    float* __restrict__ out) {
    __shared__ float s_best[2][POSB];
    __shared__ int s_bk[2][POSB];

    const int t = threadIdx.x;
    const int half = t >> 7;  // 0: k in [0,256), 1: k in [256,512)
    const int tl = t & 127;   // position-local index

    const int pbase = blockIdx.x * POSB;  // 128-aligned -> single batch/block
    const int b = pbase >> 12;
    const int hwb = pbase & 4095;

    // Both halves load the SAME position tl (each half scans different rows).
    const float* xb = x + (size_t)b * (DIM * HW) + (hwb + tl);

    float xr[DIM];
#pragma unroll
    for (int d = 0; d < DIM; ++d) xr[d] = xb[(size_t)d * HW];
    // Pin x in VGPRs (asm = defining use -> no remat/sink; verified R7).
#pragma unroll
    for (int d = 0; d < DIM; d += 8) {
        asm volatile("" : "+v"(xr[d + 0]), "+v"(xr[d + 1]), "+v"(xr[d + 2]),
                          "+v"(xr[d + 3]), "+v"(xr[d + 4]), "+v"(xr[d + 5]),
                          "+v"(xr[d + 6]), "+v"(xr[d + 7]));
    }

    float xsq = 0.f;
#pragma unroll
    for (int d = 0; d < DIM; ++d) xsq = fmaf(xr[d], xr[d], xsq);

    float best = 3.4e38f;
    int bk = 0;
    const int kbeg = half * KHALF;

    DECL_BUF(bA)
    DECL_BUF(bB)

    // Software pipeline, prefetch distance = 1 row.
    LOADROW(bA, kbeg)
    for (int kk = 0; kk < KHALF - 2; kk += 2) {
        const int k0 = kbeg + kk;
        LOADROW(bB, k0 + 1)
        FMAROW(bA, k0)
        LOADROW(bA, k0 + 2)
        FMAROW(bB, k0 + 1)
    }
    LOADROW(bB, kbeg + KHALF - 1)
    FMAROW(bA, kbeg + KHALF - 2)
    FMAROW(bB, kbeg + KHALF - 1)

    s_best[half][tl] = best;
    s_bk[half][tl] = bk;
    __syncthreads();

    // Both halves compute the winner for position tl; each writes ONE copy.
    float bl = s_best[0][tl];
    int kl = s_bk[0][tl];
    float bu = s_best[1][tl];
    int ku = s_bk[1][tl];
    int kw = (bu < bl) ? ku : kl;  // ties -> lower k (argmin first index)

    const float4* eb = reinterpret_cast<const float4*>(e + kw * DIM);
    float* o = out + (size_t)half * XELEMS + (size_t)b * (DIM * HW) + (hwb + tl);
#pragma unroll
    for (int i = 0; i < DIM / 4; ++i) {
        float4 v = eb[i];
        o[(size_t)(4 * i + 0) * HW] = v.x;
        o[(size_t)(4 * i + 1) * HW] = v.y;
        o[(size_t)(4 * i + 2) * HW] = v.z;
        o[(size_t)(4 * i + 3) * HW] = v.w;
    }
}

extern "C" void kernel_launch(void* const* d_in, const int* in_sizes, int n_in,
                              void* d_out, int out_size, void* d_ws, size_t ws_size,
                              hipStream_t stream) {
    const float* x = (const float*)d_in[0];
    const float* e = (const float*)d_in[1];
    float* out = (float*)d_out;
    float* esq = (float*)d_ws;  // 512 floats of scratch

    vq_esq_kernel<<<1, NUM_EMB, 0, stream>>>(e, esq);
    vq_main_kernel<<<NPOS / POSB, 256, 0, stream>>>(x, e, esq, out);
}